// Round 4
// baseline (447.710 us; speedup 1.0000x reference)
//
#include <hip/hip_runtime.h>
#include <math.h>

// ChamferDistance: B=4, N=M=8192, 3-D fp32 points.
// out[0] = mean_i sqrt(min_j d2)*w  +  mean_j sqrt(min_i d2)
//
// MFMA formulation (R6+): d2 = qsq + (rsq - 2 q.r) as a K=5 dot on
// v_mfma_f32_32x32x16_f16 (32 refs x 32 queries = 1024 pairs/inst):
//   A (refs)    = (-2rx,-2ry,-2rz, rsq_hi, rsq_lo, 0,0,0) f16, lanes 0-31
//   B (queries) = (  qx,  qy,  qz,   1,      1,    0,0,0) f16, lanes 0-31
// lanes 32-63 (k=8..15) zero. D: col=lane&31=query; 16 regs x lane-half =
// 32 refs -> per-lane fminf fold (ISel -> v_min3_f32) + one shfl_xor(32).
//
// R17: FUSED single-kernel restructure. R9-R16 falsified every K-loop
// scheduling theory (ILP/occupancy/dispatch/AGPR/pipelining/fold-count/
// setprio all ~invariant at nn~22us), and zero-overlap serial accounting
// of the K-loop only reaches ~12.6us -> the residual ~9us lives OUTSIDE
// the loop: 2048 un-overlapped per-block staging prologues (scalar L2
// loads + barrier with no compute to hide under) + per-block Q setup +
// the 2MB partials round-trip + reduce dispatch. New structure:
//   grid (32,8) = 256 blocks (1/CU), 512 thr (8 waves, 2/SIMD), QPW=32.
//   Each block: Q setup ONCE, then 8 chunks of 1024 refs through
//   double-buffered LDS with register prefetch (issue chunk c+1 loads ->
//   compute chunk c -> convert+ds_write c+1 -> barrier), so global
//   latency hides under 32 MFMAs/wave/chunk. Per-query min finishes
//   in-block -> sqrt/weight/block-sum -> one atomicAdd. No partials, no
//   reduce kernel. Sum-tree reorder error ~1e-6 << 3.7e-3 threshold
//   (min itself exact & identical). out zeroed via hipMemsetAsync
//   (capturable). NEVER read MFMA D regs via inline asm (R14/R15 race).

#define EPS 1e-8f

typedef _Float16 f16x8 __attribute__((ext_vector_type(8)));
typedef float    f32x16 __attribute__((ext_vector_type(16)));

constexpr int B_    = 4;
constexpr int N_    = 8192;          // points per batch (N == M)
constexpr int TPB   = 512;           // 8 waves
constexpr int QPW   = 32;            // queries per wave (1 MFMA tile)
constexpr int QPB   = 8 * QPW;       // 256 queries per block
constexpr int NCH   = 8;             // ref chunks, looped in-kernel
constexpr int CHUNK = N_ / NCH;      // 1024 refs per chunk (16 KB staged)
constexpr int PPT   = CHUNK / TPB;   // 2 points staged per thread per chunk

// Verified fold: exact min, order-free; clang pattern-matches the
// fminf(fminf(a,b),acc) chain to v_min3_f32 with proper MFMA hazard
// handling. DO NOT replace with inline asm (R14/R15: stale-register race).
#define FOLD(d, ma, mb)                                         \
    _Pragma("unroll")                                           \
    for (int r = 0; r < 8; r += 2)                              \
        ma = fminf(fminf(d[r], d[r + 1]), ma);                  \
    _Pragma("unroll")                                           \
    for (int r = 8; r < 16; r += 2)                             \
        mb = fminf(fminf(d[r], d[r + 1]), mb);

// grid: (N/QPB=32, 2*B=8) = 256 blocks, one per CU.
__global__ __launch_bounds__(TPB, 2)
void chamfer_fused_kernel(const float* __restrict__ src,
                          const float* __restrict__ tgt,
                          const float* __restrict__ w,
                          float* __restrict__ out)
{
    // double buffer + 64 zero slots (half==1 lanes broadcast-read zeros)
    __shared__ f16x8 sref[2 * CHUNK + 64];
    __shared__ float ss[TPB / 64];

    const int zb  = blockIdx.y;
    const int dir = zb >> 2;            // 0: src queries tgt, 1: tgt queries src
    const int b   = zb & 3;
    const float* Rraw = (dir ? src : tgt) + (size_t)b * N_ * 3;
    const float* Qraw = (dir ? tgt : src) + (size_t)b * N_ * 3;

    const int tid  = threadIdx.x;
    const int lane = tid & 63;
    const int wv   = tid >> 6;
    const int l31  = lane & 31;
    const int half = lane >> 5;          // 0: carries data (k=0..7), 1: zeros
    const int qb   = blockIdx.x * QPB + wv * QPW;

    const _Float16 h0 = (_Float16)0.f;
    const _Float16 h1 = (_Float16)1.f;

    // ---- Q fragment (once per block-lifetime, amortized over all 8192 refs)
    f16x8 B0 = {h0, h0, h0, h0, h0, h0, h0, h0};
    float qs0 = 0.f;
    if (half == 0) {
        const float* q0 = Qraw + (size_t)(qb + l31) * 3;
        _Float16 ax = (_Float16)q0[0], ay = (_Float16)q0[1], az = (_Float16)q0[2];
        float fax = (float)ax, fay = (float)ay, faz = (float)az;
        B0 = f16x8{ax, ay, az, h1, h1, h0, h0, h0};
        qs0 = fax * fax + fay * fay + faz * faz;
    }

    // ---- zero pad (persistent across chunks)
    if (tid < 64) {
        f16x8 z = {h0, h0, h0, h0, h0, h0, h0, h0};
        sref[2 * CHUNK + tid] = z;
    }

    // ---- stage chunk 0 into buffer 0
    float px[PPT], py[PPT], pz[PPT];
#pragma unroll
    for (int i = 0; i < PPT; ++i) {
        const float* rp = Rraw + (size_t)(tid + i * TPB) * 3;
        px[i] = rp[0]; py[i] = rp[1]; pz[i] = rp[2];
    }
#pragma unroll
    for (int i = 0; i < PPT; ++i) {
        _Float16 hx = (_Float16)px[i], hy = (_Float16)py[i], hz = (_Float16)pz[i];
        float fx = (float)hx, fy = (float)hy, fz = (float)hz;
        float rsq = fx * fx + fy * fy + fz * fz;
        _Float16 rh = (_Float16)rsq;
        _Float16 rl = (_Float16)(rsq - (float)rh);
        sref[tid + i * TPB] = f16x8{(_Float16)(-2.f * fx), (_Float16)(-2.f * fy),
                                    (_Float16)(-2.f * fz), rh, rl, h0, h0, h0};
    }
    __syncthreads();

    const f32x16 zc = {};
    const int step = (half == 0) ? 32 : 0;
    float mna = 3.0e38f, mnb = 3.0e38f;

    // ---- chunk loop: prefetch c+1 (regs) || compute c || write c+1 || barrier
    for (int c = 0; c < NCH; ++c) {
        if (c + 1 < NCH) {
#pragma unroll
            for (int i = 0; i < PPT; ++i) {
                const float* rp = Rraw + (size_t)((c + 1) * CHUNK + tid + i * TPB) * 3;
                px[i] = rp[0]; py[i] = rp[1]; pz[i] = rp[2];   // issue; use deferred
            }
        }

        // compute on buffer c&1: 32 A-fragments, depth-1 ping-pong
        int idx = (half == 0) ? ((c & 1) * CHUNK + l31) : (2 * CHUNK);
        f16x8 a = sref[idx];
        idx += step;
        f32x16 dA = __builtin_amdgcn_mfma_f32_32x32x16_f16(a, B0, zc, 0, 0, 0);
        a = sref[idx];
        idx += step;
        for (int s = 0; s < 15; ++s) {
            f32x16 dB = __builtin_amdgcn_mfma_f32_32x32x16_f16(a, B0, zc, 0, 0, 0);
            a = sref[idx];
            idx += step;
            FOLD(dA, mna, mnb)
            dA = __builtin_amdgcn_mfma_f32_32x32x16_f16(a, B0, zc, 0, 0, 0);
            a = sref[idx];
            idx += step;
            FOLD(dB, mna, mnb)
        }
        {
            f32x16 dB = __builtin_amdgcn_mfma_f32_32x32x16_f16(a, B0, zc, 0, 0, 0);
            FOLD(dA, mna, mnb)
            FOLD(dB, mna, mnb)
        }

        if (c + 1 < NCH) {
            const int wb = ((c + 1) & 1) * CHUNK;
#pragma unroll
            for (int i = 0; i < PPT; ++i) {
                _Float16 hx = (_Float16)px[i], hy = (_Float16)py[i], hz = (_Float16)pz[i];
                float fx = (float)hx, fy = (float)hy, fz = (float)hz;
                float rsq = fx * fx + fy * fy + fz * fz;
                _Float16 rh = (_Float16)rsq;
                _Float16 rl = (_Float16)(rsq - (float)rh);
                sref[wb + tid + i * TPB] = f16x8{(_Float16)(-2.f * fx), (_Float16)(-2.f * fy),
                                                 (_Float16)(-2.f * fz), rh, rl, h0, h0, h0};
            }
        }
        __syncthreads();
    }

    // ---- finish: merge lane halves, sqrt, weight, block sum, one atomic
    float mn = fminf(mna, mnb);
    mn = fminf(mn, __shfl_xor(mn, 32));
    float val = 0.f;
    if (half == 0) {
        float d = sqrtf(fmaxf(mn + qs0, 0.f) + EPS);
        val = dir ? d : d * w[(size_t)b * N_ + qb + l31];
    }
#pragma unroll
    for (int off = 32; off > 0; off >>= 1) val += __shfl_down(val, off);
    if (lane == 0) ss[wv] = val;
    __syncthreads();
    if (tid == 0) {
        float s = 0.f;
#pragma unroll
        for (int i = 0; i < TPB / 64; ++i) s += ss[i];
        atomicAdd(out, s * (1.0f / (float)(B_ * N_)));
    }
}

extern "C" void kernel_launch(void* const* d_in, const int* in_sizes, int n_in,
                              void* d_out, int out_size, void* d_ws, size_t ws_size,
                              hipStream_t stream)
{
    const float* src = (const float*)d_in[0];   // (B, N, 3)
    const float* tgt = (const float*)d_in[1];   // (B, M, 3)
    const float* w   = (const float*)d_in[2];   // (B, N)
    float* out = (float*)d_out;

    // zero the accumulator (capturable async memset; atomics add into it)
    hipMemsetAsync(out, 0, sizeof(float), stream);

    dim3 grid(N_ / QPB, 2 * B_);   // 32 x 8 = 256 blocks, one per CU
    chamfer_fused_kernel<<<grid, TPB, 0, stream>>>(src, tgt, w, out);
}

// Round 5
// 100.807 us; speedup vs baseline: 4.4413x; 4.4413x over previous
//
#include <hip/hip_runtime.h>
#include <math.h>

// ChamferDistance: B=4, N=M=8192, 3-D fp32 points.
// out[0] = mean_i sqrt(min_j d2)*w  +  mean_j sqrt(min_i d2)
//
// MFMA formulation (R6+): d2 = qsq + (rsq - 2 q.r) as a K=5 dot on
// v_mfma_f32_32x32x16_f16 (32 refs x 32 queries = 1024 pairs/inst):
//   A (refs)    = (-2rx,-2ry,-2rz, rsq_hi, rsq_lo, 0,0,0) f16, lanes 0-31
//   B (queries) = (  qx,  qy,  qz,   1,      1,    0,0,0) f16, lanes 0-31
// lanes 32-63 (k=8..15) zero. D: col=lane&31=query; 16 regs x lane-half =
// 32 refs -> per-lane fminf fold (ISel -> v_min3_f32) + one shfl_xor(32).
//
// R18: fused, WITHOUT cross-chunk register prefetch. R17's fused kernel
// was correct (absmax 0.0 -> fused-sum numerics proven) but moved 2 GB of
// HBM traffic (WRITE 1.26 GB with no global stores besides one atomic ->
// scratch spills; 2 GB @ 4.6 TB/s = the whole 447us). Spill suspect: the
// px/py/pz prefetch registers live across the fully-unrolled 32-MFMA
// compute body inside a runtime chunk loop. This round keeps the fusion
// wins (Q-setup x1 instead of x8, no 2MB partials round-trip, no reduce
// dispatch, 1/8th the staging prologues) but stages chunks in a plain
// 2-barrier phase with zero values live across compute, and uses the
// EXACT R13-verified 4-wave/B0+B1/ping-pong K-loop. launch_bounds(256,1)
// relaxes the VGPR cap (live ~110) so the allocator never spills.
// Predict: fused dispatch 12-20us, WRITE_SIZE ~0; total ~55-62us.
// NEVER read MFMA D regs via inline asm (R14/R15 race).

#define EPS 1e-8f

typedef _Float16 f16x8 __attribute__((ext_vector_type(8)));
typedef float    f32x16 __attribute__((ext_vector_type(16)));

constexpr int B_    = 4;
constexpr int N_    = 8192;          // points per batch (N == M)
constexpr int TPB   = 256;           // 4 waves (R13-verified shape)
constexpr int QPW   = 64;            // queries per wave (2 tiles of 32)
constexpr int QPB   = 4 * QPW;       // 256 queries per block
constexpr int NCH   = 8;             // ref chunks, looped in-kernel
constexpr int CHUNK = N_ / NCH;      // 1024 refs per chunk (16 KB staged)
constexpr int PPT   = CHUNK / TPB;   // 4 points staged per thread per chunk

// Verified fold: exact min, order-free; clang pattern-matches the
// fminf(fminf(a,b),acc) chain to v_min3_f32 with proper MFMA hazard
// handling. DO NOT replace with inline asm (R14/R15: stale-register race).
#define FOLD(d, ma, mb)                                         \
    _Pragma("unroll")                                           \
    for (int r = 0; r < 8; r += 2)                              \
        ma = fminf(fminf(d[r], d[r + 1]), ma);                  \
    _Pragma("unroll")                                           \
    for (int r = 8; r < 16; r += 2)                             \
        mb = fminf(fminf(d[r], d[r + 1]), mb);

// grid: (N/QPB=32, 2*B=8) = 256 blocks, one per CU.
__global__ __launch_bounds__(TPB, 1)
void chamfer_fused_kernel(const float* __restrict__ src,
                          const float* __restrict__ tgt,
                          const float* __restrict__ w,
                          float* __restrict__ out)
{
    __shared__ f16x8 sref[CHUNK + 64];   // single buffer + 64 zero slots
    __shared__ float ss[TPB / 64];

    const int zb  = blockIdx.y;
    const int dir = zb >> 2;            // 0: src queries tgt, 1: tgt queries src
    const int b   = zb & 3;
    const float* Rraw = (dir ? src : tgt) + (size_t)b * N_ * 3;
    const float* Qraw = (dir ? tgt : src) + (size_t)b * N_ * 3;

    const int tid  = threadIdx.x;
    const int lane = tid & 63;
    const int wv   = tid >> 6;
    const int l31  = lane & 31;
    const int half = lane >> 5;          // 0: carries data (k=0..7), 1: zeros
    const int qb   = blockIdx.x * QPB + wv * QPW;

    const _Float16 h0 = (_Float16)0.f;
    const _Float16 h1 = (_Float16)1.f;

    // ---- Q fragments ONCE per block (amortized over all 8192 refs)
    f16x8 B0 = {h0, h0, h0, h0, h0, h0, h0, h0};
    f16x8 B1 = B0;
    float qs0 = 0.f, qs1 = 0.f;
    if (half == 0) {
        const float* q0 = Qraw + (size_t)(qb + l31) * 3;
        const float* q1 = Qraw + (size_t)(qb + 32 + l31) * 3;
        _Float16 ax = (_Float16)q0[0], ay = (_Float16)q0[1], az = (_Float16)q0[2];
        _Float16 bx = (_Float16)q1[0], by = (_Float16)q1[1], bz = (_Float16)q1[2];
        float fax = (float)ax, fay = (float)ay, faz = (float)az;
        float fbx = (float)bx, fby = (float)by, fbz = (float)bz;
        B0 = f16x8{ax, ay, az, h1, h1, h0, h0, h0};
        B1 = f16x8{bx, by, bz, h1, h1, h0, h0, h0};
        qs0 = fax * fax + fay * fay + faz * faz;
        qs1 = fbx * fbx + fby * fby + fbz * fbz;
    }

    // ---- zero pad (persistent across chunks)
    if (tid < 64) {
        f16x8 z = {h0, h0, h0, h0, h0, h0, h0, h0};
        sref[CHUNK + tid] = z;
    }

    const f32x16 zc = {};
    const int step = (half == 0) ? 32 : 0;
    float mn0a = 3.0e38f, mn0b = 3.0e38f, mn1a = 3.0e38f, mn1b = 3.0e38f;

    // ---- stage chunk 0
#pragma unroll
    for (int i = 0; i < PPT; ++i) {
        const float* rp = Rraw + (size_t)(tid + i * TPB) * 3;
        _Float16 hx = (_Float16)rp[0], hy = (_Float16)rp[1], hz = (_Float16)rp[2];
        float fx = (float)hx, fy = (float)hy, fz = (float)hz;
        float rsq = fx * fx + fy * fy + fz * fz;
        _Float16 rh = (_Float16)rsq;
        _Float16 rl = (_Float16)(rsq - (float)rh);
        sref[tid + i * TPB] = f16x8{(_Float16)(-2.f * fx), (_Float16)(-2.f * fy),
                                    (_Float16)(-2.f * fz), rh, rl, h0, h0, h0};
    }
    __syncthreads();

    // ---- chunk loop: compute(c) -> barrier -> stage(c+1) -> barrier
    for (int c = 0; c < NCH; ++c) {
        // R13-verified K-loop: 32 A-fragments, depth-1 ping-pong, 2 B-tiles
        int idx = (half == 0) ? l31 : CHUNK;
        f16x8 a = sref[idx];
        idx += step;
        f32x16 dA0 = __builtin_amdgcn_mfma_f32_32x32x16_f16(a, B0, zc, 0, 0, 0);
        f32x16 dA1 = __builtin_amdgcn_mfma_f32_32x32x16_f16(a, B1, zc, 0, 0, 0);
        a = sref[idx];
        idx += step;
        for (int s = 0; s < 15; ++s) {
            f32x16 dB0 = __builtin_amdgcn_mfma_f32_32x32x16_f16(a, B0, zc, 0, 0, 0);
            f32x16 dB1 = __builtin_amdgcn_mfma_f32_32x32x16_f16(a, B1, zc, 0, 0, 0);
            a = sref[idx];
            idx += step;
            FOLD(dA0, mn0a, mn0b)
            FOLD(dA1, mn1a, mn1b)
            dA0 = __builtin_amdgcn_mfma_f32_32x32x16_f16(a, B0, zc, 0, 0, 0);
            dA1 = __builtin_amdgcn_mfma_f32_32x32x16_f16(a, B1, zc, 0, 0, 0);
            a = sref[idx];
            idx += step;
            FOLD(dB0, mn0a, mn0b)
            FOLD(dB1, mn1a, mn1b)
        }
        {
            f32x16 dB0 = __builtin_amdgcn_mfma_f32_32x32x16_f16(a, B0, zc, 0, 0, 0);
            f32x16 dB1 = __builtin_amdgcn_mfma_f32_32x32x16_f16(a, B1, zc, 0, 0, 0);
            FOLD(dA0, mn0a, mn0b)
            FOLD(dA1, mn1a, mn1b)
            FOLD(dB0, mn0a, mn0b)
            FOLD(dB1, mn1a, mn1b)
        }

        if (c + 1 < NCH) {
            __syncthreads();             // all waves done reading chunk c
#pragma unroll
            for (int i = 0; i < PPT; ++i) {
                const float* rp = Rraw + (size_t)((c + 1) * CHUNK + tid + i * TPB) * 3;
                _Float16 hx = (_Float16)rp[0], hy = (_Float16)rp[1], hz = (_Float16)rp[2];
                float fx = (float)hx, fy = (float)hy, fz = (float)hz;
                float rsq = fx * fx + fy * fy + fz * fz;
                _Float16 rh = (_Float16)rsq;
                _Float16 rl = (_Float16)(rsq - (float)rh);
                sref[tid + i * TPB] = f16x8{(_Float16)(-2.f * fx), (_Float16)(-2.f * fy),
                                            (_Float16)(-2.f * fz), rh, rl, h0, h0, h0};
            }
            __syncthreads();             // chunk c+1 visible to all waves
        }
    }

    // ---- finish: merge lane halves, sqrt, weight, block sum, one atomic
    float mn0 = fminf(mn0a, mn0b);
    float mn1 = fminf(mn1a, mn1b);
    mn0 = fminf(mn0, __shfl_xor(mn0, 32));
    mn1 = fminf(mn1, __shfl_xor(mn1, 32));
    float val = 0.f;
    if (half == 0) {
        float d0 = sqrtf(fmaxf(mn0 + qs0, 0.f) + EPS);
        float d1 = sqrtf(fmaxf(mn1 + qs1, 0.f) + EPS);
        val = dir ? (d0 + d1)
                  : (d0 * w[(size_t)b * N_ + qb + l31] +
                     d1 * w[(size_t)b * N_ + qb + 32 + l31]);
    }
#pragma unroll
    for (int off = 32; off > 0; off >>= 1) val += __shfl_down(val, off);
    if (lane == 0) ss[wv] = val;
    __syncthreads();
    if (tid == 0) {
        float s = 0.f;
#pragma unroll
        for (int i = 0; i < TPB / 64; ++i) s += ss[i];
        atomicAdd(out, s * (1.0f / (float)(B_ * N_)));
    }
}

extern "C" void kernel_launch(void* const* d_in, const int* in_sizes, int n_in,
                              void* d_out, int out_size, void* d_ws, size_t ws_size,
                              hipStream_t stream)
{
    const float* src = (const float*)d_in[0];   // (B, N, 3)
    const float* tgt = (const float*)d_in[1];   // (B, M, 3)
    const float* w   = (const float*)d_in[2];   // (B, N)
    float* out = (float*)d_out;

    // zero the accumulator (capturable async memset; atomics add into it)
    hipMemsetAsync(out, 0, sizeof(float), stream);

    dim3 grid(N_ / QPB, 2 * B_);   // 32 x 8 = 256 blocks, one per CU
    chamfer_fused_kernel<<<grid, TPB, 0, stream>>>(src, tgt, w, out);
}

// Round 8
// 80.490 us; speedup vs baseline: 5.5623x; 1.2524x over previous
//
#include <hip/hip_runtime.h>
#include <math.h>

// ChamferDistance: B=4, N=M=8192, 3-D fp32 points.
// out[0] = mean_i sqrt(min_j d2)*w  +  mean_j sqrt(min_i d2)
//
// MFMA formulation (R6+): d2 = qsq + (rsq - 2 q.r) as a K=5 dot on
// v_mfma_f32_32x32x16_f16 (32 refs x 32 queries = 1024 pairs/inst):
//   A (refs)    = (-2rx,-2ry,-2rz, rsq_hi, rsq_lo, 0,0,0) f16, lanes 0-31
//   B (queries) = (  qx,  qy,  qz,   1,      1,    0,0,0) f16, lanes 0-31
// lanes 32-63 (k=8..15) zero. D: col=lane&31=query; 16 regs x lane-half =
// 32 refs -> per-lane med3-min fold + one shfl_xor(32).
//
// R21 (R19/R20 both died to "container failed twice" — no compile or test
// output; likely broker flakiness, but source varied this round to
// de-correlate: dropped the R16 setprio wrappers, which measured null).
// Payload hypothesis unchanged: FOLD via v_med3_f32. R18's fused run
// calibrated the pipe model: MfmaUtil 13% == predicted 14.6% (32x32x16
// mfma = 32 SIMD-cyc; matrix floor 6.8us/SIMD), but VALUBusy 45% == ~25k
// VALU instr/wave vs ~5k modeled -> fold is ~5x the min3 floor. Cause:
// fminf -> llvm.minnum; backend inserts canonicalize (v_max x,x) on every
// MFMA-derived input (mfma results not known-canonical) and doesn't fuse
// min3. That VALU bloat (~14us/SIMD) is nn's scheduling-invariant residual
// (R9-R16 consistent). Fix WITHOUT inline asm (R14/R15: asm reading MFMA
// D regs races on missing hazard nops): __builtin_amdgcn_fmed3f(a,b,-3e38)
// == min(a,b), 1 instr, direct ISel, no canonicalize, normal SSA.
// Predict: nn ~22 -> ~15us, total 75.0 -> ~66-68us, absmax 0.0.
// If flat: fold was already lean; VALU theory falsified.

#define EPS 1e-8f

typedef _Float16 f16x8 __attribute__((ext_vector_type(8)));
typedef float    f32x16 __attribute__((ext_vector_type(16)));

constexpr int B_    = 4;
constexpr int N_    = 8192;          // points per batch (N == M)
constexpr int TPB   = 256;           // 4 waves
constexpr int QPW   = 64;            // queries per wave (2 tiles of 32)
constexpr int QPB   = 4 * QPW;       // 256 queries per block
constexpr int RCH   = 8;             // ref chunks (grid.y)
constexpr int CHUNK = N_ / RCH;      // 1024 refs staged per block (16 KB)
constexpr int RB    = 64;            // reduce blocks (R13-verified order)

// NEG_BIG <= any d2 (|d2| <= ~1.7e10 from f16-bounded inputs), so
// med3(a,b,NEG_BIG) == min(a,b) exactly. Finite (not -inf) so no
// inf-specific InstCombine can re-fold it into minnum+canonicalize.
#define NEG_BIG (-3.0e38f)

// med3-min fold: ONE VALU op per min, no canonicalize, no inline asm
// (R14/R15: asm reading MFMA D regs races). 16 ops per 16-value fragment.
#define FOLD(d, ma, mb)                                                    \
    _Pragma("unroll")                                                      \
    for (int r = 0; r < 8; r += 2)                                         \
        ma = __builtin_amdgcn_fmed3f(                                      \
                 __builtin_amdgcn_fmed3f(d[r], d[r + 1], NEG_BIG),         \
                 ma, NEG_BIG);                                             \
    _Pragma("unroll")                                                      \
    for (int r = 8; r < 16; r += 2)                                        \
        mb = __builtin_amdgcn_fmed3f(                                      \
                 __builtin_amdgcn_fmed3f(d[r], d[r + 1], NEG_BIG),         \
                 mb, NEG_BIG);

// grid: (N/QPB=32, RCH=8, 2*B=8) = 2048 blocks.
// part layout: part[(zb*RCH + c)*N + q]  (zb = dir*4+b), 2 MB total.
__global__ __launch_bounds__(TPB, 4)
void nn_mfma_kernel(const float* __restrict__ src, const float* __restrict__ tgt,
                    float* __restrict__ part, float* __restrict__ out)
{
    __shared__ f16x8 sref[CHUNK + 64];   // +64: zero slots (also absorb tail reads)

    if (blockIdx.x == 0 && blockIdx.y == 0 && blockIdx.z == 0 && threadIdx.x == 0)
        out[0] = 0.f;                    // reduce (next dispatch) atomicAdds

    const int zb  = blockIdx.z;
    const int dir = zb >> 2;            // 0: src queries tgt, 1: tgt queries src
    const int b   = zb & 3;
    const float* Rraw = (dir ? src : tgt) + ((size_t)b * N_ + (size_t)blockIdx.y * CHUNK) * 3;
    const float* Qraw = (dir ? tgt : src) + (size_t)b * N_ * 3;
    float* opart = part + ((size_t)zb * RCH + blockIdx.y) * N_;

    const int tid = threadIdx.x;
    const _Float16 h0 = (_Float16)0.f;
    const _Float16 h1 = (_Float16)1.f;

    // stage + quantize refs inline: (-2x,-2y,-2z, rsq_hi, rsq_lo, 0,0,0)
    for (int k = tid; k < CHUNK; k += TPB) {
        const float* rp = Rraw + (size_t)k * 3;
        _Float16 hx = (_Float16)rp[0], hy = (_Float16)rp[1], hz = (_Float16)rp[2];
        float fx = (float)hx, fy = (float)hy, fz = (float)hz;
        float rsq = fx * fx + fy * fy + fz * fz;
        _Float16 rh = (_Float16)rsq;
        _Float16 rl = (_Float16)(rsq - (float)rh);
        f16x8 a = {(_Float16)(-2.f * fx), (_Float16)(-2.f * fy),
                   (_Float16)(-2.f * fz), rh, rl, h0, h0, h0};
        sref[k] = a;
    }
    if (tid < 64) {
        f16x8 z = {h0, h0, h0, h0, h0, h0, h0, h0};
        sref[CHUNK + tid] = z;
    }

    const int lane = tid & 63;
    const int wv   = tid >> 6;
    const int l31  = lane & 31;
    const int half = lane >> 5;          // 0: carries data (k=0..7), 1: zeros
    const int qb   = blockIdx.x * QPB + wv * QPW;

    // B fragments quantized inline; lanes 32-63 stay zero (k=8..15)
    f16x8 B0 = {h0, h0, h0, h0, h0, h0, h0, h0};
    f16x8 B1 = B0;
    float qs0 = 0.f, qs1 = 0.f;
    if (half == 0) {
        const float* q0 = Qraw + (size_t)(qb + l31) * 3;
        const float* q1 = Qraw + (size_t)(qb + 32 + l31) * 3;
        _Float16 ax = (_Float16)q0[0], ay = (_Float16)q0[1], az = (_Float16)q0[2];
        _Float16 bx = (_Float16)q1[0], by = (_Float16)q1[1], bz = (_Float16)q1[2];
        float fax = (float)ax, fay = (float)ay, faz = (float)az;
        float fbx = (float)bx, fby = (float)by, fbz = (float)bz;
        B0 = f16x8{ax, ay, az, h1, h1, h0, h0, h0};
        B1 = f16x8{bx, by, bz, h1, h1, h0, h0, h0};
        qs0 = fax * fax + fay * fay + faz * faz;
        qs1 = fbx * fbx + fby * fby + fbz * fbz;
    }
    __syncthreads();

    const f32x16 zc = {};

    // Depth-1 pipelined K-loop over 32 A-fragments, unrolled x2 (ping-pong,
    // no register copies): fold fragment k-1's D while fragment k's MFMAs
    // are in flight.
    int idx = (half == 0) ? l31 : CHUNK;
    const int step = (half == 0) ? 32 : 0;
    float mn0a = 3.0e38f, mn0b = 3.0e38f, mn1a = 3.0e38f, mn1b = 3.0e38f;

    f16x8 a = sref[idx];
    idx += step;
    f32x16 dA0 = __builtin_amdgcn_mfma_f32_32x32x16_f16(a, B0, zc, 0, 0, 0);
    f32x16 dA1 = __builtin_amdgcn_mfma_f32_32x32x16_f16(a, B1, zc, 0, 0, 0);
    a = sref[idx];
    idx += step;
    for (int s = 0; s < 15; ++s) {
        f32x16 dB0 = __builtin_amdgcn_mfma_f32_32x32x16_f16(a, B0, zc, 0, 0, 0);
        f32x16 dB1 = __builtin_amdgcn_mfma_f32_32x32x16_f16(a, B1, zc, 0, 0, 0);
        a = sref[idx];
        idx += step;
        FOLD(dA0, mn0a, mn0b)
        FOLD(dA1, mn1a, mn1b)
        dA0 = __builtin_amdgcn_mfma_f32_32x32x16_f16(a, B0, zc, 0, 0, 0);
        dA1 = __builtin_amdgcn_mfma_f32_32x32x16_f16(a, B1, zc, 0, 0, 0);
        a = sref[idx];
        idx += step;
        FOLD(dB0, mn0a, mn0b)
        FOLD(dB1, mn1a, mn1b)
    }
    {
        f32x16 dB0 = __builtin_amdgcn_mfma_f32_32x32x16_f16(a, B0, zc, 0, 0, 0);
        f32x16 dB1 = __builtin_amdgcn_mfma_f32_32x32x16_f16(a, B1, zc, 0, 0, 0);
        FOLD(dA0, mn0a, mn0b)
        FOLD(dA1, mn1a, mn1b)
        FOLD(dB0, mn0a, mn0b)
        FOLD(dB1, mn1a, mn1b)
    }

    float mn0 = fminf(mn0a, mn0b);
    float mn1 = fminf(mn1a, mn1b);
    // rows split across lane halves: one xor-32 merge covers all 32 refs/tile
    mn0 = fminf(mn0, __shfl_xor(mn0, 32));
    mn1 = fminf(mn1, __shfl_xor(mn1, 32));
    if (half == 0) {
        opart[qb + l31]      = fmaxf(mn0 + qs0, 0.f);   // plain store, no init
        opart[qb + 32 + l31] = fmaxf(mn1 + qs1, 0.f);
    }
}

// reduce: per query min over RCH partials -> sqrt -> weight -> sum ->
// atomicAdd into out[0] (zeroed by nn). 2 MB of partials, L2-resident.
// R13-verified summation order (absmax 0.0) — keep byte-identical.
__global__ __launch_bounds__(TPB)
void reduce_kernel(const float* __restrict__ part,
                   const float* __restrict__ w,
                   float* __restrict__ out)
{
    const int Q = 2 * B_ * N_;               // 65536 queries
    const float invBN = 1.0f / (float)(B_ * N_);

    float sum = 0.0f;
    for (int t = blockIdx.x * TPB + threadIdx.x; t < Q; t += RB * TPB) {
        const int zb = t >> 13;              // t / N_
        const int qn = t & (N_ - 1);
        const float* p = part + ((size_t)zb * RCH) * N_ + qn;
        float m = p[0];
#pragma unroll
        for (int c = 1; c < RCH; ++c) m = fminf(m, p[(size_t)c * N_]);
        float d = sqrtf(m + EPS);
        sum += (zb < 4) ? d * w[(size_t)zb * N_ + qn] : d;
    }
    sum *= invBN;

    __shared__ float ss[TPB / 64];
    int lane = threadIdx.x & 63;
    int wid  = threadIdx.x >> 6;
#pragma unroll
    for (int off = 32; off > 0; off >>= 1) sum += __shfl_down(sum, off);
    if (lane == 0) ss[wid] = sum;
    __syncthreads();
    if (threadIdx.x == 0) {
        float s = 0.0f;
#pragma unroll
        for (int i = 0; i < TPB / 64; ++i) s += ss[i];
        atomicAdd(out, s);
    }
}

extern "C" void kernel_launch(void* const* d_in, const int* in_sizes, int n_in,
                              void* d_out, int out_size, void* d_ws, size_t ws_size,
                              hipStream_t stream)
{
    const float* src = (const float*)d_in[0];   // (B, N, 3)
    const float* tgt = (const float*)d_in[1];   // (B, M, 3)
    const float* w   = (const float*)d_in[2];   // (B, N)
    float* out = (float*)d_out;

    float* part = (float*)d_ws;   // [2*B][RCH][N] = 2 MB, fully overwritten

    dim3 grid(N_ / QPB, RCH, 2 * B_);   // 32 x 8 x 8 = 2048 blocks
    nn_mfma_kernel<<<grid, TPB, 0, stream>>>(src, tgt, part, out);

    reduce_kernel<<<RB, TPB, 0, stream>>>(part, w, out);
}

// Round 9
// 75.734 us; speedup vs baseline: 5.9116x; 1.0628x over previous
//
#include <hip/hip_runtime.h>
#include <math.h>

// ChamferDistance: B=4, N=M=8192, 3-D fp32 points.
// out[0] = mean_i sqrt(min_j d2)*w  +  mean_j sqrt(min_i d2)
//
// MFMA formulation (R6+): d2 = qsq + (rsq - 2 q.r) as a K=5 dot on
// v_mfma_f32_32x32x16_f16 (32 refs x 32 queries = 1024 pairs/inst):
//   A (refs)    = (-2rx,-2ry,-2rz, rsq_hi, rsq_lo, 0,0,0) f16, lanes 0-31
//   B (queries) = (  qx,  qy,  qz,   1,      1,    0,0,0) f16, lanes 0-31
// lanes 32-63 (k=8..15) zero. D: col=lane&31=query; 16 regs x lane-half =
// 32 refs -> per-lane fminf fold (ISel -> v_min3_f32) + one shfl_xor(32).
//
// R22: med3 experiment (R21, 80.5us vs 75.0 baseline) FALSIFIED the
// canonicalize theory quantitatively: med3's fixed 1 instr/value was
// +3.4us-predicted/+5.3us-measured vs baseline -> the fminf chain was
// ALREADY min3-fused at 0.5 instr/value. Fold is at its VALU floor; R18's
// VALUBusy 45% was a derived-counter artifact. FOLD reverted to fminf.
// New lever (only latency term the R13 D-ping-pong doesn't cover): each
// a=sref[idx] ds_read_b128 (~120cy) was consumed after only ~32cy of FOLD
// -> ~80cy exposed lgkmcnt per fragment when co-resident waves are phase-
// aligned. Fix: depth-2 A-prefetch (two A regs aA/aB, +4 VGPR), each
// loaded a full iteration (~100+cy) ahead of its consuming MFMA. The
// extra tail load (f32) lands in the zero pad, never consumed. Pure
// LDS-read reorder -> bit-identical output.
// Predict: nn -2..-5us -> total ~70-73us. If flat: LDS latency already
// wave-hidden; remaining budget is MFMA effective rate -> near-roofline.
// NEVER read MFMA D regs via inline asm (R14/R15 race).

#define EPS 1e-8f

typedef _Float16 f16x8 __attribute__((ext_vector_type(8)));
typedef float    f32x16 __attribute__((ext_vector_type(16)));

constexpr int B_    = 4;
constexpr int N_    = 8192;          // points per batch (N == M)
constexpr int TPB   = 256;           // 4 waves
constexpr int QPW   = 64;            // queries per wave (2 tiles of 32)
constexpr int QPB   = 4 * QPW;       // 256 queries per block
constexpr int RCH   = 8;             // ref chunks (grid.y)
constexpr int CHUNK = N_ / RCH;      // 1024 refs staged per block (16 KB)
constexpr int RB    = 64;            // reduce blocks (R13-verified order)

// Verified fold: exact min, order-free; clang fuses fminf(fminf(a,b),acc)
// to v_min3_f32 (PROVEN at floor by the R21 med3 A/B: explicit 1-instr/
// value med3 was +5us). DO NOT replace with inline asm (R14/R15 race) or
// med3 (R21: 2x fold ops).
#define FOLD(d, ma, mb)                                         \
    _Pragma("unroll")                                           \
    for (int r = 0; r < 8; r += 2)                              \
        ma = fminf(fminf(d[r], d[r + 1]), ma);                  \
    _Pragma("unroll")                                           \
    for (int r = 8; r < 16; r += 2)                             \
        mb = fminf(fminf(d[r], d[r + 1]), mb);

// grid: (N/QPB=32, RCH=8, 2*B=8) = 2048 blocks.
// part layout: part[(zb*RCH + c)*N + q]  (zb = dir*4+b), 2 MB total.
__global__ __launch_bounds__(TPB, 4)
void nn_mfma_kernel(const float* __restrict__ src, const float* __restrict__ tgt,
                    float* __restrict__ part, float* __restrict__ out)
{
    __shared__ f16x8 sref[CHUNK + 64];   // +64: zero slots (also absorb tail reads)

    if (blockIdx.x == 0 && blockIdx.y == 0 && blockIdx.z == 0 && threadIdx.x == 0)
        out[0] = 0.f;                    // reduce (next dispatch) atomicAdds

    const int zb  = blockIdx.z;
    const int dir = zb >> 2;            // 0: src queries tgt, 1: tgt queries src
    const int b   = zb & 3;
    const float* Rraw = (dir ? src : tgt) + ((size_t)b * N_ + (size_t)blockIdx.y * CHUNK) * 3;
    const float* Qraw = (dir ? tgt : src) + (size_t)b * N_ * 3;
    float* opart = part + ((size_t)zb * RCH + blockIdx.y) * N_;

    const int tid = threadIdx.x;
    const _Float16 h0 = (_Float16)0.f;
    const _Float16 h1 = (_Float16)1.f;

    // stage + quantize refs inline: (-2x,-2y,-2z, rsq_hi, rsq_lo, 0,0,0)
    for (int k = tid; k < CHUNK; k += TPB) {
        const float* rp = Rraw + (size_t)k * 3;
        _Float16 hx = (_Float16)rp[0], hy = (_Float16)rp[1], hz = (_Float16)rp[2];
        float fx = (float)hx, fy = (float)hy, fz = (float)hz;
        float rsq = fx * fx + fy * fy + fz * fz;
        _Float16 rh = (_Float16)rsq;
        _Float16 rl = (_Float16)(rsq - (float)rh);
        f16x8 a = {(_Float16)(-2.f * fx), (_Float16)(-2.f * fy),
                   (_Float16)(-2.f * fz), rh, rl, h0, h0, h0};
        sref[k] = a;
    }
    if (tid < 64) {
        f16x8 z = {h0, h0, h0, h0, h0, h0, h0, h0};
        sref[CHUNK + tid] = z;
    }

    const int lane = tid & 63;
    const int wv   = tid >> 6;
    const int l31  = lane & 31;
    const int half = lane >> 5;          // 0: carries data (k=0..7), 1: zeros
    const int qb   = blockIdx.x * QPB + wv * QPW;

    // B fragments quantized inline; lanes 32-63 stay zero (k=8..15)
    f16x8 B0 = {h0, h0, h0, h0, h0, h0, h0, h0};
    f16x8 B1 = B0;
    float qs0 = 0.f, qs1 = 0.f;
    if (half == 0) {
        const float* q0 = Qraw + (size_t)(qb + l31) * 3;
        const float* q1 = Qraw + (size_t)(qb + 32 + l31) * 3;
        _Float16 ax = (_Float16)q0[0], ay = (_Float16)q0[1], az = (_Float16)q0[2];
        _Float16 bx = (_Float16)q1[0], by = (_Float16)q1[1], bz = (_Float16)q1[2];
        float fax = (float)ax, fay = (float)ay, faz = (float)az;
        float fbx = (float)bx, fby = (float)by, fbz = (float)bz;
        B0 = f16x8{ax, ay, az, h1, h1, h0, h0, h0};
        B1 = f16x8{bx, by, bz, h1, h1, h0, h0, h0};
        qs0 = fax * fax + fay * fay + faz * faz;
        qs1 = fbx * fbx + fby * fby + fbz * fbz;
    }
    __syncthreads();

    const f32x16 zc = {};

    // K-loop over 32 A-fragments: D ping-pong (depth-1, R13) + A-prefetch
    // (depth-2, R22). Frag trace: pre: aA=f0, aB=f1, dA=mfma(f0), aA=f2.
    // iter s: dB=mfma(f(2s+1)), aB=f(2s+3), fold dA, dA=mfma(f(2s+2)),
    // aA=f(2s+4), fold dB. Final aA load (f32) hits the zero pad, unused.
    int idx = (half == 0) ? l31 : CHUNK;
    const int step = (half == 0) ? 32 : 0;
    float mn0a = 3.0e38f, mn0b = 3.0e38f, mn1a = 3.0e38f, mn1b = 3.0e38f;

    f16x8 aA = sref[idx];
    idx += step;
    f16x8 aB = sref[idx];
    idx += step;
    f32x16 dA0 = __builtin_amdgcn_mfma_f32_32x32x16_f16(aA, B0, zc, 0, 0, 0);
    f32x16 dA1 = __builtin_amdgcn_mfma_f32_32x32x16_f16(aA, B1, zc, 0, 0, 0);
    aA = sref[idx];
    idx += step;
    for (int s = 0; s < 15; ++s) {
        f32x16 dB0 = __builtin_amdgcn_mfma_f32_32x32x16_f16(aB, B0, zc, 0, 0, 0);
        f32x16 dB1 = __builtin_amdgcn_mfma_f32_32x32x16_f16(aB, B1, zc, 0, 0, 0);
        aB = sref[idx];
        idx += step;
        FOLD(dA0, mn0a, mn0b)
        FOLD(dA1, mn1a, mn1b)
        dA0 = __builtin_amdgcn_mfma_f32_32x32x16_f16(aA, B0, zc, 0, 0, 0);
        dA1 = __builtin_amdgcn_mfma_f32_32x32x16_f16(aA, B1, zc, 0, 0, 0);
        aA = sref[idx];
        idx += step;
        FOLD(dB0, mn0a, mn0b)
        FOLD(dB1, mn1a, mn1b)
    }
    {
        f32x16 dB0 = __builtin_amdgcn_mfma_f32_32x32x16_f16(aB, B0, zc, 0, 0, 0);
        f32x16 dB1 = __builtin_amdgcn_mfma_f32_32x32x16_f16(aB, B1, zc, 0, 0, 0);
        FOLD(dA0, mn0a, mn0b)
        FOLD(dA1, mn1a, mn1b)
        FOLD(dB0, mn0a, mn0b)
        FOLD(dB1, mn1a, mn1b)
    }

    float mn0 = fminf(mn0a, mn0b);
    float mn1 = fminf(mn1a, mn1b);
    // rows split across lane halves: one xor-32 merge covers all 32 refs/tile
    mn0 = fminf(mn0, __shfl_xor(mn0, 32));
    mn1 = fminf(mn1, __shfl_xor(mn1, 32));
    if (half == 0) {
        opart[qb + l31]      = fmaxf(mn0 + qs0, 0.f);   // plain store, no init
        opart[qb + 32 + l31] = fmaxf(mn1 + qs1, 0.f);
    }
}

// reduce: per query min over RCH partials -> sqrt -> weight -> sum ->
// atomicAdd into out[0] (zeroed by nn). 2 MB of partials, L2-resident.
// R13-verified summation order (absmax 0.0) — keep byte-identical.
__global__ __launch_bounds__(TPB)
void reduce_kernel(const float* __restrict__ part,
                   const float* __restrict__ w,
                   float* __restrict__ out)
{
    const int Q = 2 * B_ * N_;               // 65536 queries
    const float invBN = 1.0f / (float)(B_ * N_);

    float sum = 0.0f;
    for (int t = blockIdx.x * TPB + threadIdx.x; t < Q; t += RB * TPB) {
        const int zb = t >> 13;              // t / N_
        const int qn = t & (N_ - 1);
        const float* p = part + ((size_t)zb * RCH) * N_ + qn;
        float m = p[0];
#pragma unroll
        for (int c = 1; c < RCH; ++c) m = fminf(m, p[(size_t)c * N_]);
        float d = sqrtf(m + EPS);
        sum += (zb < 4) ? d * w[(size_t)zb * N_ + qn] : d;
    }
    sum *= invBN;

    __shared__ float ss[TPB / 64];
    int lane = threadIdx.x & 63;
    int wid  = threadIdx.x >> 6;
#pragma unroll
    for (int off = 32; off > 0; off >>= 1) sum += __shfl_down(sum, off);
    if (lane == 0) ss[wid] = sum;
    __syncthreads();
    if (threadIdx.x == 0) {
        float s = 0.0f;
#pragma unroll
        for (int i = 0; i < TPB / 64; ++i) s += ss[i];
        atomicAdd(out, s);
    }
}

extern "C" void kernel_launch(void* const* d_in, const int* in_sizes, int n_in,
                              void* d_out, int out_size, void* d_ws, size_t ws_size,
                              hipStream_t stream)
{
    const float* src = (const float*)d_in[0];   // (B, N, 3)
    const float* tgt = (const float*)d_in[1];   // (B, M, 3)
    const float* w   = (const float*)d_in[2];   // (B, N)
    float* out = (float*)d_out;

    float* part = (float*)d_ws;   // [2*B][RCH][N] = 2 MB, fully overwritten

    dim3 grid(N_ / QPB, RCH, 2 * B_);   // 32 x 8 x 8 = 2048 blocks
    nn_mfma_kernel<<<grid, TPB, 0, stream>>>(src, tgt, part, out);

    reduce_kernel<<<RB, TPB, 0, stream>>>(part, w, out);
}